// Round 17
// baseline (369.966 us; speedup 1.0000x reference)
//
#include <hip/hip_runtime.h>
#include <hip/hip_bf16.h>

#define N_NODES 50000
#define N_EDGES 600000
#define DD 128
#define N_LAYERS 6
#define SCAN_BLOCKS 196   // ceil(50000/256)
#define N_CHUNKS 3125     // 50000 / 16 exactly

#define XB16_T 1600000
#define ZERO_T 50000
#define PREPW_T 196608
#define PREP_TOTAL (XB16_T + ZERO_T + PREPW_T)

typedef __attribute__((ext_vector_type(8))) short bf16x8;
typedef __attribute__((ext_vector_type(4))) float floatx4;

__device__ __forceinline__ unsigned short f2b(float f) {
    unsigned u = __float_as_uint(f);
    unsigned r = (u + 0x7FFFu + ((u >> 16) & 1u)) >> 16;
    return (unsigned short)r;
}

// ---------------- merged prep ----------------

__global__ void prep_all(const float* __restrict__ x, unsigned short* __restrict__ hx,
                         const float* __restrict__ Wl, const float* __restrict__ Wr,
                         unsigned short* __restrict__ WT2,
                         int* __restrict__ deg, int* __restrict__ cursor) {
    int gid = blockIdx.x * blockDim.x + threadIdx.x;
    if (gid < XB16_T) {
        int b = gid * 4;
        float4 v = *(const float4*)(x + b);
        ushort4 o;
        o.x = f2b(v.x); o.y = f2b(v.y); o.z = f2b(v.z); o.w = f2b(v.w);
        *(ushort4*)(hx + b) = o;
    } else if (gid < XB16_T + ZERO_T) {
        int i = gid - XB16_T;
        deg[i] = 0; cursor[i] = 0;
    } else if (gid < PREP_TOTAL) {
        int idx = gid - (XB16_T + ZERO_T);
        int l   = idx >> 15;
        int rem = idx & 32767;
        int n   = rem >> 8;
        int k2  = rem & 255;
        const float* W = (k2 < 128 ? Wl : Wr) + (size_t)l * DD * DD + (size_t)(k2 & 127) * DD + n;
        WT2[idx] = f2b(*W);
    }
}

// ---------------- CSR build ----------------

__global__ void count_deg(const int* __restrict__ dst, int* __restrict__ deg) {
    int e = blockIdx.x * blockDim.x + threadIdx.x;
    if (e < N_EDGES) atomicAdd(&deg[dst[e]], 1);
}

__global__ void block_sums(const int* __restrict__ deg, int* __restrict__ bsum) {
    __shared__ int s[256];
    int tid = threadIdx.x;
    int i = blockIdx.x * 256 + tid;
    int v = (i < N_NODES) ? deg[i] : 0;
    s[tid] = v;
    __syncthreads();
    #pragma unroll
    for (int off = 128; off > 0; off >>= 1) {
        if (tid < off) s[tid] += s[tid + off];
        __syncthreads();
    }
    if (tid == 0) bsum[blockIdx.x] = s[0];
}

__global__ void scan_bsums(int* __restrict__ bsum, int* __restrict__ offsets) {
    __shared__ int s[256];
    int tid = threadIdx.x;
    int v = (tid < SCAN_BLOCKS) ? bsum[tid] : 0;
    s[tid] = v;
    __syncthreads();
    for (int off = 1; off < 256; off <<= 1) {
        int t = (tid >= off) ? s[tid - off] : 0;
        __syncthreads();
        s[tid] += t;
        __syncthreads();
    }
    if (tid < SCAN_BLOCKS) bsum[tid] = s[tid] - v;   // exclusive
    if (tid == 0) offsets[N_NODES] = N_EDGES;
}

__global__ void write_offsets(const int* __restrict__ deg, const int* __restrict__ bsum,
                              int* __restrict__ offsets, float* __restrict__ deg_inv) {
    __shared__ int s[256];
    int tid = threadIdx.x;
    int i = blockIdx.x * 256 + tid;
    int v = (i < N_NODES) ? deg[i] : 0;
    s[tid] = v;
    __syncthreads();
    for (int off = 1; off < 256; off <<= 1) {
        int t = (tid >= off) ? s[tid - off] : 0;
        __syncthreads();
        s[tid] += t;
        __syncthreads();
    }
    if (i < N_NODES) {
        offsets[i] = bsum[blockIdx.x] + s[tid] - v;
        deg_inv[i] = 1.0f / (float)(v > 1 ? v : 1);
    }
}

__global__ void fill_csr(const int* __restrict__ src, const int* __restrict__ dst,
                         const int* __restrict__ offsets, int* __restrict__ cursor,
                         int* __restrict__ csr_src) {
    int e = blockIdx.x * blockDim.x + threadIdx.x;
    if (e < N_EDGES) {
        int d = dst[e];
        int p = atomicAdd(&cursor[d], 1);
        csr_src[offsets[d] + p] = src[e];
    }
}

// ---------------- fused SAGE layer: wave-private gather -> gemm ----------------
// 391 blocks x 512 threads (8 waves), LDS = sW only (64 KB) -> 2 blocks/CU.
// Wave w owns chunk = blockIdx*8+w (16 nodes). Phase A: gather-mean those 16
// nodes (R12's exact 2-node/wave pattern, 8 items), writing bf16 agg rows to
// global. vmcnt drain. Phase B: R16's direct-A gemm on its OWN agg rows (same-CU
// L2/L1 hits by construction) + h rows; B from swizzled sW. No inter-wave sync.
// doFC: last layer fuses out = relu(C) @ fcW + fcb.

__launch_bounds__(512, 4)
__global__ void sage_layer(const unsigned short* __restrict__ H,
                           const int* __restrict__ offsets,
                           const int* __restrict__ csr_src,
                           const float* __restrict__ deg_inv,
                           const unsigned short* __restrict__ WT2,   // [128 n][256 k]
                           const float* __restrict__ bias,
                           unsigned short* __restrict__ agg,
                           unsigned short* __restrict__ Cout,
                           const float* __restrict__ fcW,
                           const float* __restrict__ fcb,
                           float* __restrict__ out,
                           int doFC) {
    __shared__ __align__(16) unsigned short sW[128 * 256];     // 64 KB

    int tid  = threadIdx.x;
    int wid  = tid >> 6, lane = tid & 63;

    // ---- fill sW (swizzled: chunk c of col stored at col*32 + (c ^ (col&7))) ----
    for (int t = tid; t < 4096; t += 512) {
        int col = t >> 5, c = t & 31;
        uint4 v = *(const uint4*)(WT2 + (size_t)col * 256 + c * 8);
        *(uint4*)(sW + ((size_t)col * 32 + (c ^ (col & 7))) * 8) = v;
    }
    __syncthreads();

    int chunk = blockIdx.x * 8 + wid;
    if (chunk >= N_CHUNKS) return;
    int row0 = chunk * 16;

    // ======== Phase A: gather-mean 16 nodes (8 x 2-node items) ========
    {
        int nodeSel = lane >> 5;
        int l32  = lane & 31;
        int grp  = l32 >> 3;
        int p    = l32 & 7;

        for (int it = 0; it < 8; ++it) {
            int node = row0 + it * 2 + nodeSel;       // < 50000 by construction
            int s0 = offsets[node], e0 = offsets[node + 1];
            float di = deg_inv[node];

            float a[16];
            #pragma unroll
            for (int i = 0; i < 16; ++i) a[i] = 0.f;

            int j = s0 + grp;
            for (; j + 4 < e0; j += 8) {
                int src1 = csr_src[j];
                int src2 = csr_src[j + 4];
                const uint4* r1 = (const uint4*)(H + (size_t)src1 * DD + p * 16);
                const uint4* r2 = (const uint4*)(H + (size_t)src2 * DD + p * 16);
                uint4 v1a = r1[0], v1b = r1[1];
                uint4 v2a = r2[0], v2b = r2[1];
                a[0] += __uint_as_float(v1a.x << 16); a[1] += __uint_as_float(v1a.x & 0xFFFF0000u);
                a[2] += __uint_as_float(v1a.y << 16); a[3] += __uint_as_float(v1a.y & 0xFFFF0000u);
                a[4] += __uint_as_float(v1a.z << 16); a[5] += __uint_as_float(v1a.z & 0xFFFF0000u);
                a[6] += __uint_as_float(v1a.w << 16); a[7] += __uint_as_float(v1a.w & 0xFFFF0000u);
                a[8] += __uint_as_float(v1b.x << 16); a[9] += __uint_as_float(v1b.x & 0xFFFF0000u);
                a[10]+= __uint_as_float(v1b.y << 16); a[11]+= __uint_as_float(v1b.y & 0xFFFF0000u);
                a[12]+= __uint_as_float(v1b.z << 16); a[13]+= __uint_as_float(v1b.z & 0xFFFF0000u);
                a[14]+= __uint_as_float(v1b.w << 16); a[15]+= __uint_as_float(v1b.w & 0xFFFF0000u);
                a[0] += __uint_as_float(v2a.x << 16); a[1] += __uint_as_float(v2a.x & 0xFFFF0000u);
                a[2] += __uint_as_float(v2a.y << 16); a[3] += __uint_as_float(v2a.y & 0xFFFF0000u);
                a[4] += __uint_as_float(v2a.z << 16); a[5] += __uint_as_float(v2a.z & 0xFFFF0000u);
                a[6] += __uint_as_float(v2a.w << 16); a[7] += __uint_as_float(v2a.w & 0xFFFF0000u);
                a[8] += __uint_as_float(v2b.x << 16); a[9] += __uint_as_float(v2b.x & 0xFFFF0000u);
                a[10]+= __uint_as_float(v2b.y << 16); a[11]+= __uint_as_float(v2b.y & 0xFFFF0000u);
                a[12]+= __uint_as_float(v2b.z << 16); a[13]+= __uint_as_float(v2b.z & 0xFFFF0000u);
                a[14]+= __uint_as_float(v2b.w << 16); a[15]+= __uint_as_float(v2b.w & 0xFFFF0000u);
            }
            if (j < e0) {
                int src1 = csr_src[j];
                const uint4* r1 = (const uint4*)(H + (size_t)src1 * DD + p * 16);
                uint4 v1a = r1[0], v1b = r1[1];
                a[0] += __uint_as_float(v1a.x << 16); a[1] += __uint_as_float(v1a.x & 0xFFFF0000u);
                a[2] += __uint_as_float(v1a.y << 16); a[3] += __uint_as_float(v1a.y & 0xFFFF0000u);
                a[4] += __uint_as_float(v1a.z << 16); a[5] += __uint_as_float(v1a.z & 0xFFFF0000u);
                a[6] += __uint_as_float(v1a.w << 16); a[7] += __uint_as_float(v1a.w & 0xFFFF0000u);
                a[8] += __uint_as_float(v1b.x << 16); a[9] += __uint_as_float(v1b.x & 0xFFFF0000u);
                a[10]+= __uint_as_float(v1b.y << 16); a[11]+= __uint_as_float(v1b.y & 0xFFFF0000u);
                a[12]+= __uint_as_float(v1b.z << 16); a[13]+= __uint_as_float(v1b.z & 0xFFFF0000u);
                a[14]+= __uint_as_float(v1b.w << 16); a[15]+= __uint_as_float(v1b.w & 0xFFFF0000u);
            }

            #pragma unroll
            for (int i = 0; i < 16; ++i) {
                a[i] += __shfl_xor(a[i], 8, 64);
                a[i] += __shfl_xor(a[i], 16, 64);
            }

            if (grp == 0) {
                uint4 o1, o2;
                o1.x = (unsigned)f2b(a[0] * di) | ((unsigned)f2b(a[1] * di) << 16);
                o1.y = (unsigned)f2b(a[2] * di) | ((unsigned)f2b(a[3] * di) << 16);
                o1.z = (unsigned)f2b(a[4] * di) | ((unsigned)f2b(a[5] * di) << 16);
                o1.w = (unsigned)f2b(a[6] * di) | ((unsigned)f2b(a[7] * di) << 16);
                o2.x = (unsigned)f2b(a[8] * di) | ((unsigned)f2b(a[9] * di) << 16);
                o2.y = (unsigned)f2b(a[10]* di) | ((unsigned)f2b(a[11]* di) << 16);
                o2.z = (unsigned)f2b(a[12]* di) | ((unsigned)f2b(a[13]* di) << 16);
                o2.w = (unsigned)f2b(a[14]* di) | ((unsigned)f2b(a[15]* di) << 16);
                uint4* dst = (uint4*)(agg + (size_t)node * DD + p * 16);
                dst[0] = o1;
                dst[1] = o2;
            }
        }
    }
    __builtin_amdgcn_s_waitcnt(0);   // agg stores visible before re-read

    // ======== Phase B: gemm on own chunk (agg rows L2-hot) ========
    int l15 = lane & 15, q = lane >> 4;

    float bcol[8];
    #pragma unroll
    for (int j = 0; j < 8; ++j) bcol[j] = bias[j * 16 + l15];

    const unsigned short* Arow = agg + (size_t)(row0 + l15) * DD;
    const unsigned short* Hrow = H   + (size_t)(row0 + l15) * DD;
    bf16x8 aF[8];
    #pragma unroll
    for (int s = 0; s < 4; ++s)
        aF[s] = *(const bf16x8*)(Arow + (s * 4 + q) * 8);
    #pragma unroll
    for (int s = 4; s < 8; ++s)
        aF[s] = *(const bf16x8*)(Hrow + (s * 4 + q - 16) * 8);

    floatx4 acc[8];
    #pragma unroll
    for (int j = 0; j < 8; ++j) acc[j] = (floatx4){0.f, 0.f, 0.f, 0.f};

    #pragma unroll
    for (int s = 0; s < 8; ++s) {
        int cglob = s * 4 + q;
        #pragma unroll
        for (int j = 0; j < 8; ++j) {
            int col = j * 16 + l15;
            bf16x8 bF = *(const bf16x8*)(sW + ((size_t)col * 32 + (cglob ^ (col & 7))) * 8);
            acc[j] = __builtin_amdgcn_mfma_f32_16x16x32_bf16(aF[s], bF, acc[j], 0, 0, 0);
        }
    }

    if (!doFC) {
        #pragma unroll
        for (int r = 0; r < 4; ++r) {
            int row = row0 + q * 4 + r;
            #pragma unroll
            for (int j = 0; j < 8; ++j) {
                float v = acc[j][r] + bcol[j];
                Cout[(size_t)row * DD + j * 16 + l15] = f2b(fmaxf(v, 0.f));
            }
        }
    } else {
        float2 fcw[8];
        #pragma unroll
        for (int j = 0; j < 8; ++j) fcw[j] = *(const float2*)(fcW + (j * 16 + l15) * 2);
        float fb0 = fcb[0], fb1 = fcb[1];
        #pragma unroll
        for (int r = 0; r < 4; ++r) {
            float p0 = 0.f, p1 = 0.f;
            #pragma unroll
            for (int j = 0; j < 8; ++j) {
                float v = fmaxf(acc[j][r] + bcol[j], 0.f);
                p0 += v * fcw[j].x;
                p1 += v * fcw[j].y;
            }
            p0 += __shfl_xor(p0, 1, 64); p1 += __shfl_xor(p1, 1, 64);
            p0 += __shfl_xor(p0, 2, 64); p1 += __shfl_xor(p1, 2, 64);
            p0 += __shfl_xor(p0, 4, 64); p1 += __shfl_xor(p1, 4, 64);
            p0 += __shfl_xor(p0, 8, 64); p1 += __shfl_xor(p1, 8, 64);
            if (l15 == 0) {
                int row = row0 + q * 4 + r;
                out[row * 2]     = p0 + fb0;
                out[row * 2 + 1] = p1 + fb1;
            }
        }
    }
}

// ---------------- launch ----------------

extern "C" void kernel_launch(void* const* d_in, const int* in_sizes, int n_in,
                              void* d_out, int out_size, void* d_ws, size_t ws_size,
                              hipStream_t stream) {
    const float* x    = (const float*)d_in[0];
    const int*   ei   = (const int*)d_in[1];
    const float* Wl   = (const float*)d_in[2];
    const float* Wr   = (const float*)d_in[3];
    const float* bl   = (const float*)d_in[4];
    const float* fcW  = (const float*)d_in[5];
    const float* fcb  = (const float*)d_in[6];
    float* out = (float*)d_out;

    const int* srcIdx = ei;
    const int* dstIdx = ei + N_EDGES;

    char* ws = (char*)d_ws;
    size_t off = 0;
    auto bump = [&](size_t bytes) { char* p = ws + off; off = (off + bytes + 255) & ~(size_t)255; return p; };
    int*   deg     = (int*)  bump(N_NODES * 4);
    int*   cursor  = (int*)  bump(N_NODES * 4);
    int*   offsets = (int*)  bump((N_NODES + 1) * 4);
    int*   bsum    = (int*)  bump(SCAN_BLOCKS * 4);
    float* deg_inv = (float*)bump(N_NODES * 4);
    int*   csr     = (int*)  bump(N_EDGES * 4);
    unsigned short* hx   = (unsigned short*)bump((size_t)N_NODES * DD * 2);
    unsigned short* hb0  = (unsigned short*)bump((size_t)N_NODES * DD * 2);
    unsigned short* hb1  = (unsigned short*)bump((size_t)N_NODES * DD * 2);
    unsigned short* agg  = (unsigned short*)bump((size_t)N_NODES * DD * 2);
    unsigned short* WT2  = (unsigned short*)bump((size_t)N_LAYERS * 128 * 256 * 2);
    (void)ws_size;

    prep_all<<<(PREP_TOTAL + 255) / 256, 256, 0, stream>>>(x, hx, Wl, Wr, WT2, deg, cursor);
    count_deg<<<(N_EDGES + 255) / 256, 256, 0, stream>>>(dstIdx, deg);
    block_sums<<<SCAN_BLOCKS, 256, 0, stream>>>(deg, bsum);
    scan_bsums<<<1, 256, 0, stream>>>(bsum, offsets);
    write_offsets<<<SCAN_BLOCKS, 256, 0, stream>>>(deg, bsum, offsets, deg_inv);
    fill_csr<<<(N_EDGES + 255) / 256, 256, 0, stream>>>(srcIdx, dstIdx, offsets, cursor, csr);

    const unsigned short* hin = hx;
    unsigned short* hbuf[2] = { hb0, hb1 };
    for (int l = 0; l < N_LAYERS; ++l) {
        int last = (l == N_LAYERS - 1);
        unsigned short* hout = hbuf[l & 1];
        sage_layer<<<(N_CHUNKS + 7) / 8, 512, 0, stream>>>(
            hin, offsets, csr, deg_inv, WT2 + (size_t)l * 128 * 256, bl + (size_t)l * DD,
            agg, hout, fcW, fcb, out, last);
        hin = hout;
    }
}

// Round 18
// 364.047 us; speedup vs baseline: 1.0163x; 1.0163x over previous
//
#include <hip/hip_runtime.h>
#include <hip/hip_bf16.h>

#define N_NODES 50000
#define N_EDGES 600000
#define DD 128
#define N_LAYERS 6
#define SCAN_BLOCKS 196   // ceil(50000/256)
#define N_CHUNKS 3125     // 50000 / 16 exactly
#define AGG_BLOCKS 6256

#define XB16_T 1600000
#define ZERO_T 50000
#define PREPW_T 196608
#define PREP_TOTAL (XB16_T + ZERO_T + PREPW_T)

typedef __attribute__((ext_vector_type(8))) short bf16x8;
typedef __attribute__((ext_vector_type(4))) float floatx4;

__device__ __forceinline__ unsigned short f2b(float f) {
    unsigned u = __float_as_uint(f);
    unsigned r = (u + 0x7FFFu + ((u >> 16) & 1u)) >> 16;
    return (unsigned short)r;
}

// ---------------- merged prep ----------------

__global__ void prep_all(const float* __restrict__ x, unsigned short* __restrict__ hx,
                         const float* __restrict__ Wl, const float* __restrict__ Wr,
                         unsigned short* __restrict__ WT2,
                         int* __restrict__ deg, int* __restrict__ cursor) {
    int gid = blockIdx.x * blockDim.x + threadIdx.x;
    if (gid < XB16_T) {
        int b = gid * 4;
        float4 v = *(const float4*)(x + b);
        ushort4 o;
        o.x = f2b(v.x); o.y = f2b(v.y); o.z = f2b(v.z); o.w = f2b(v.w);
        *(ushort4*)(hx + b) = o;
    } else if (gid < XB16_T + ZERO_T) {
        int i = gid - XB16_T;
        deg[i] = 0; cursor[i] = 0;
    } else if (gid < PREP_TOTAL) {
        int idx = gid - (XB16_T + ZERO_T);
        int l   = idx >> 15;
        int rem = idx & 32767;
        int n   = rem >> 8;
        int k2  = rem & 255;
        const float* W = (k2 < 128 ? Wl : Wr) + (size_t)l * DD * DD + (size_t)(k2 & 127) * DD + n;
        WT2[idx] = f2b(*W);
    }
}

// ---------------- CSR build ----------------

__global__ void count_deg(const int* __restrict__ dst, int* __restrict__ deg) {
    int e = blockIdx.x * blockDim.x + threadIdx.x;
    if (e < N_EDGES) atomicAdd(&deg[dst[e]], 1);
}

__global__ void block_sums(const int* __restrict__ deg, int* __restrict__ bsum) {
    __shared__ int s[256];
    int tid = threadIdx.x;
    int i = blockIdx.x * 256 + tid;
    int v = (i < N_NODES) ? deg[i] : 0;
    s[tid] = v;
    __syncthreads();
    #pragma unroll
    for (int off = 128; off > 0; off >>= 1) {
        if (tid < off) s[tid] += s[tid + off];
        __syncthreads();
    }
    if (tid == 0) bsum[blockIdx.x] = s[0];
}

__global__ void scan_bsums(int* __restrict__ bsum, int* __restrict__ offsets) {
    __shared__ int s[256];
    int tid = threadIdx.x;
    int v = (tid < SCAN_BLOCKS) ? bsum[tid] : 0;
    s[tid] = v;
    __syncthreads();
    for (int off = 1; off < 256; off <<= 1) {
        int t = (tid >= off) ? s[tid - off] : 0;
        __syncthreads();
        s[tid] += t;
        __syncthreads();
    }
    if (tid < SCAN_BLOCKS) bsum[tid] = s[tid] - v;   // exclusive
    if (tid == 0) offsets[N_NODES] = N_EDGES;
}

__global__ void write_offsets(const int* __restrict__ deg, const int* __restrict__ bsum,
                              int* __restrict__ offsets, float* __restrict__ deg_inv) {
    __shared__ int s[256];
    int tid = threadIdx.x;
    int i = blockIdx.x * 256 + tid;
    int v = (i < N_NODES) ? deg[i] : 0;
    s[tid] = v;
    __syncthreads();
    for (int off = 1; off < 256; off <<= 1) {
        int t = (tid >= off) ? s[tid - off] : 0;
        __syncthreads();
        s[tid] += t;
        __syncthreads();
    }
    if (i < N_NODES) {
        offsets[i] = bsum[blockIdx.x] + s[tid] - v;
        deg_inv[i] = 1.0f / (float)(v > 1 ? v : 1);
    }
}

__global__ void fill_csr(const int* __restrict__ src, const int* __restrict__ dst,
                         const int* __restrict__ offsets, int* __restrict__ cursor,
                         int* __restrict__ csr_src) {
    int e = blockIdx.x * blockDim.x + threadIdx.x;
    if (e < N_EDGES) {
        int d = dst[e];
        int p = atomicAdd(&cursor[d], 1);
        csr_src[offsets[d] + p] = src[e];
    }
}

// ---------------- mean aggregation: R12-exact (best measured) ----------------

__global__ void aggregate(const unsigned short* __restrict__ hin, const int* __restrict__ offsets,
                          const int* __restrict__ csr_src, const float* __restrict__ deg_inv,
                          unsigned short* __restrict__ agg) {
    int w    = threadIdx.x >> 6;
    int lane = threadIdx.x & 63;
    int nodeSel = lane >> 5;
    int l32  = lane & 31;
    int grp  = l32 >> 3;
    int p    = l32 & 7;

    int b = blockIdx.x;
    int x = b & 7, s = b >> 3;
    int hc = 16 * (s >> 1) + 2 * x + (s & 1);
    int node = hc * 8 + 2 * w + nodeSel;
    if (node >= N_NODES) return;
    int s0 = offsets[node], e0 = offsets[node + 1];
    float di = deg_inv[node];

    float a[16];
    #pragma unroll
    for (int i = 0; i < 16; ++i) a[i] = 0.f;

    const unsigned short* base = hin;
    int j = s0 + grp;
    for (; j + 4 < e0; j += 8) {
        int src1 = csr_src[j];
        int src2 = csr_src[j + 4];
        const uint4* r1 = (const uint4*)(base + (size_t)src1 * DD + p * 16);
        const uint4* r2 = (const uint4*)(base + (size_t)src2 * DD + p * 16);
        uint4 v1a = r1[0], v1b = r1[1];
        uint4 v2a = r2[0], v2b = r2[1];
        a[0] += __uint_as_float(v1a.x << 16); a[1] += __uint_as_float(v1a.x & 0xFFFF0000u);
        a[2] += __uint_as_float(v1a.y << 16); a[3] += __uint_as_float(v1a.y & 0xFFFF0000u);
        a[4] += __uint_as_float(v1a.z << 16); a[5] += __uint_as_float(v1a.z & 0xFFFF0000u);
        a[6] += __uint_as_float(v1a.w << 16); a[7] += __uint_as_float(v1a.w & 0xFFFF0000u);
        a[8] += __uint_as_float(v1b.x << 16); a[9] += __uint_as_float(v1b.x & 0xFFFF0000u);
        a[10]+= __uint_as_float(v1b.y << 16); a[11]+= __uint_as_float(v1b.y & 0xFFFF0000u);
        a[12]+= __uint_as_float(v1b.z << 16); a[13]+= __uint_as_float(v1b.z & 0xFFFF0000u);
        a[14]+= __uint_as_float(v1b.w << 16); a[15]+= __uint_as_float(v1b.w & 0xFFFF0000u);
        a[0] += __uint_as_float(v2a.x << 16); a[1] += __uint_as_float(v2a.x & 0xFFFF0000u);
        a[2] += __uint_as_float(v2a.y << 16); a[3] += __uint_as_float(v2a.y & 0xFFFF0000u);
        a[4] += __uint_as_float(v2a.z << 16); a[5] += __uint_as_float(v2a.z & 0xFFFF0000u);
        a[6] += __uint_as_float(v2a.w << 16); a[7] += __uint_as_float(v2a.w & 0xFFFF0000u);
        a[8] += __uint_as_float(v2b.x << 16); a[9] += __uint_as_float(v2b.x & 0xFFFF0000u);
        a[10]+= __uint_as_float(v2b.y << 16); a[11]+= __uint_as_float(v2b.y & 0xFFFF0000u);
        a[12]+= __uint_as_float(v2b.z << 16); a[13]+= __uint_as_float(v2b.z & 0xFFFF0000u);
        a[14]+= __uint_as_float(v2b.w << 16); a[15]+= __uint_as_float(v2b.w & 0xFFFF0000u);
    }
    if (j < e0) {
        int src1 = csr_src[j];
        const uint4* r1 = (const uint4*)(base + (size_t)src1 * DD + p * 16);
        uint4 v1a = r1[0], v1b = r1[1];
        a[0] += __uint_as_float(v1a.x << 16); a[1] += __uint_as_float(v1a.x & 0xFFFF0000u);
        a[2] += __uint_as_float(v1a.y << 16); a[3] += __uint_as_float(v1a.y & 0xFFFF0000u);
        a[4] += __uint_as_float(v1a.z << 16); a[5] += __uint_as_float(v1a.z & 0xFFFF0000u);
        a[6] += __uint_as_float(v1a.w << 16); a[7] += __uint_as_float(v1a.w & 0xFFFF0000u);
        a[8] += __uint_as_float(v1b.x << 16); a[9] += __uint_as_float(v1b.x & 0xFFFF0000u);
        a[10]+= __uint_as_float(v1b.y << 16); a[11]+= __uint_as_float(v1b.y & 0xFFFF0000u);
        a[12]+= __uint_as_float(v1b.z << 16); a[13]+= __uint_as_float(v1b.z & 0xFFFF0000u);
        a[14]+= __uint_as_float(v1b.w << 16); a[15]+= __uint_as_float(v1b.w & 0xFFFF0000u);
    }

    #pragma unroll
    for (int i = 0; i < 16; ++i) {
        a[i] += __shfl_xor(a[i], 8, 64);
        a[i] += __shfl_xor(a[i], 16, 64);
    }

    if (grp == 0) {
        uint4 o1, o2;
        o1.x = (unsigned)f2b(a[0] * di) | ((unsigned)f2b(a[1] * di) << 16);
        o1.y = (unsigned)f2b(a[2] * di) | ((unsigned)f2b(a[3] * di) << 16);
        o1.z = (unsigned)f2b(a[4] * di) | ((unsigned)f2b(a[5] * di) << 16);
        o1.w = (unsigned)f2b(a[6] * di) | ((unsigned)f2b(a[7] * di) << 16);
        o2.x = (unsigned)f2b(a[8] * di) | ((unsigned)f2b(a[9] * di) << 16);
        o2.y = (unsigned)f2b(a[10]* di) | ((unsigned)f2b(a[11]* di) << 16);
        o2.z = (unsigned)f2b(a[12]* di) | ((unsigned)f2b(a[13]* di) << 16);
        o2.w = (unsigned)f2b(a[14]* di) | ((unsigned)f2b(a[15]* di) << 16);
        uint4* dst = (uint4*)(agg + (size_t)node * DD + p * 16);
        dst[0] = o1;
        dst[1] = o2;
    }
}

// ---------------- half-W GEMM: 64 cols per block, 32 KB LDS, 24 waves/CU ----------------
// 782 blocks x 512 threads. Block b: colHalf = b&1, waves handle chunk=(b>>1)*8+wid.
// Wave computes 16 rows x 64 cols (4 col-tiles, 32 MFMA). A direct from global.

__launch_bounds__(512, 6)
__global__ void gemm_half(const unsigned short* __restrict__ Agg,
                          const unsigned short* __restrict__ H,
                          const unsigned short* __restrict__ WT2,   // [128 n][256 k]
                          const float* __restrict__ bias,
                          unsigned short* __restrict__ Cout) {
    __shared__ __align__(16) unsigned short sW[64 * 256];      // 32 KB

    int tid  = threadIdx.x;
    int wid  = tid >> 6, lane = tid & 63;
    int l15  = lane & 15, q = lane >> 4;
    int colHalf = blockIdx.x & 1;
    int cb = colHalf * 64;

    // fill sW: 64 local cols, swizzled chunk c at colL*32 + (c ^ (colL&7))
    for (int t = tid; t < 2048; t += 512) {
        int colL = t >> 5, c = t & 31;
        uint4 v = *(const uint4*)(WT2 + (size_t)(cb + colL) * 256 + c * 8);
        *(uint4*)(sW + ((size_t)colL * 32 + (c ^ (colL & 7))) * 8) = v;
    }
    __syncthreads();

    int chunk = (blockIdx.x >> 1) * 8 + wid;
    if (chunk >= N_CHUNKS) return;
    int row0 = chunk * 16;

    float bcol[4];
    #pragma unroll
    for (int j = 0; j < 4; ++j) bcol[j] = bias[cb + j * 16 + l15];

    const unsigned short* Arow = Agg + (size_t)(row0 + l15) * DD;
    const unsigned short* Hrow = H   + (size_t)(row0 + l15) * DD;

    floatx4 acc[4];
    #pragma unroll
    for (int j = 0; j < 4; ++j) acc[j] = (floatx4){0.f, 0.f, 0.f, 0.f};

    // first half of K (agg), then second half (h) — lower register pressure
    {
        bf16x8 aF[4];
        #pragma unroll
        for (int s = 0; s < 4; ++s)
            aF[s] = *(const bf16x8*)(Arow + (s * 4 + q) * 8);
        #pragma unroll
        for (int s = 0; s < 4; ++s) {
            int cglob = s * 4 + q;
            #pragma unroll
            for (int j = 0; j < 4; ++j) {
                int colL = j * 16 + l15;
                bf16x8 bF = *(const bf16x8*)(sW + ((size_t)colL * 32 + (cglob ^ (colL & 7))) * 8);
                acc[j] = __builtin_amdgcn_mfma_f32_16x16x32_bf16(aF[s], bF, acc[j], 0, 0, 0);
            }
        }
    }
    {
        bf16x8 aF[4];
        #pragma unroll
        for (int s = 0; s < 4; ++s)
            aF[s] = *(const bf16x8*)(Hrow + (s * 4 + q) * 8);
        #pragma unroll
        for (int s = 4; s < 8; ++s) {
            int cglob = s * 4 + q;
            #pragma unroll
            for (int j = 0; j < 4; ++j) {
                int colL = j * 16 + l15;
                bf16x8 bF = *(const bf16x8*)(sW + ((size_t)colL * 32 + (cglob ^ (colL & 7))) * 8);
                acc[j] = __builtin_amdgcn_mfma_f32_16x16x32_bf16(aF[s - 4], bF, acc[j], 0, 0, 0);
            }
        }
    }

    #pragma unroll
    for (int r = 0; r < 4; ++r) {
        int row = row0 + q * 4 + r;
        #pragma unroll
        for (int j = 0; j < 4; ++j) {
            float v = acc[j][r] + bcol[j];
            Cout[(size_t)row * DD + cb + j * 16 + l15] = f2b(fmaxf(v, 0.f));
        }
    }
}

// ---------------- full-width GEMM (R16) — used for the last layer (fused FC) ----------------

__launch_bounds__(512, 4)
__global__ void gemm_full(const unsigned short* __restrict__ Agg,
                          const unsigned short* __restrict__ H,
                          const unsigned short* __restrict__ WT2,
                          const float* __restrict__ bias,
                          const float* __restrict__ fcW,
                          const float* __restrict__ fcb,
                          float* __restrict__ out) {
    __shared__ __align__(16) unsigned short sW[128 * 256];     // 64 KB

    int tid  = threadIdx.x;
    int wid  = tid >> 6, lane = tid & 63;
    int l15  = lane & 15, q = lane >> 4;

    for (int t = tid; t < 4096; t += 512) {
        int col = t >> 5, c = t & 31;
        uint4 v = *(const uint4*)(WT2 + (size_t)col * 256 + c * 8);
        *(uint4*)(sW + ((size_t)col * 32 + (c ^ (col & 7))) * 8) = v;
    }
    __syncthreads();

    int chunk = blockIdx.x * 8 + wid;
    if (chunk >= N_CHUNKS) return;
    int row0 = chunk * 16;

    float bcol[8];
    #pragma unroll
    for (int j = 0; j < 8; ++j) bcol[j] = bias[j * 16 + l15];

    const unsigned short* Arow = Agg + (size_t)(row0 + l15) * DD;
    const unsigned short* Hrow = H   + (size_t)(row0 + l15) * DD;
    bf16x8 aF[8];
    #pragma unroll
    for (int s = 0; s < 4; ++s)
        aF[s] = *(const bf16x8*)(Arow + (s * 4 + q) * 8);
    #pragma unroll
    for (int s = 4; s < 8; ++s)
        aF[s] = *(const bf16x8*)(Hrow + (s * 4 + q - 16) * 8);

    floatx4 acc[8];
    #pragma unroll
    for (int j = 0; j < 8; ++j) acc[j] = (floatx4){0.f, 0.f, 0.f, 0.f};

    #pragma unroll
    for (int s = 0; s < 8; ++s) {
        int cglob = s * 4 + q;
        #pragma unroll
        for (int j = 0; j < 8; ++j) {
            int col = j * 16 + l15;
            bf16x8 bF = *(const bf16x8*)(sW + ((size_t)col * 32 + (cglob ^ (col & 7))) * 8);
            acc[j] = __builtin_amdgcn_mfma_f32_16x16x32_bf16(aF[s], bF, acc[j], 0, 0, 0);
        }
    }

    float2 fcw[8];
    #pragma unroll
    for (int j = 0; j < 8; ++j) fcw[j] = *(const float2*)(fcW + (j * 16 + l15) * 2);
    float fb0 = fcb[0], fb1 = fcb[1];
    #pragma unroll
    for (int r = 0; r < 4; ++r) {
        float p0 = 0.f, p1 = 0.f;
        #pragma unroll
        for (int j = 0; j < 8; ++j) {
            float v = fmaxf(acc[j][r] + bcol[j], 0.f);
            p0 += v * fcw[j].x;
            p1 += v * fcw[j].y;
        }
        p0 += __shfl_xor(p0, 1, 64); p1 += __shfl_xor(p1, 1, 64);
        p0 += __shfl_xor(p0, 2, 64); p1 += __shfl_xor(p1, 2, 64);
        p0 += __shfl_xor(p0, 4, 64); p1 += __shfl_xor(p1, 4, 64);
        p0 += __shfl_xor(p0, 8, 64); p1 += __shfl_xor(p1, 8, 64);
        if (l15 == 0) {
            int row = row0 + q * 4 + r;
            out[row * 2]     = p0 + fb0;
            out[row * 2 + 1] = p1 + fb1;
        }
    }
}

// ---------------- launch ----------------

extern "C" void kernel_launch(void* const* d_in, const int* in_sizes, int n_in,
                              void* d_out, int out_size, void* d_ws, size_t ws_size,
                              hipStream_t stream) {
    const float* x    = (const float*)d_in[0];
    const int*   ei   = (const int*)d_in[1];
    const float* Wl   = (const float*)d_in[2];
    const float* Wr   = (const float*)d_in[3];
    const float* bl   = (const float*)d_in[4];
    const float* fcW  = (const float*)d_in[5];
    const float* fcb  = (const float*)d_in[6];
    float* out = (float*)d_out;

    const int* srcIdx = ei;
    const int* dstIdx = ei + N_EDGES;

    char* ws = (char*)d_ws;
    size_t off = 0;
    auto bump = [&](size_t bytes) { char* p = ws + off; off = (off + bytes + 255) & ~(size_t)255; return p; };
    int*   deg     = (int*)  bump(N_NODES * 4);
    int*   cursor  = (int*)  bump(N_NODES * 4);
    int*   offsets = (int*)  bump((N_NODES + 1) * 4);
    int*   bsum    = (int*)  bump(SCAN_BLOCKS * 4);
    float* deg_inv = (float*)bump(N_NODES * 4);
    int*   csr     = (int*)  bump(N_EDGES * 4);
    unsigned short* hx   = (unsigned short*)bump((size_t)N_NODES * DD * 2);
    unsigned short* hb0  = (unsigned short*)bump((size_t)N_NODES * DD * 2);
    unsigned short* hb1  = (unsigned short*)bump((size_t)N_NODES * DD * 2);
    unsigned short* agg  = (unsigned short*)bump((size_t)N_NODES * DD * 2);
    unsigned short* WT2  = (unsigned short*)bump((size_t)N_LAYERS * 128 * 256 * 2);
    (void)ws_size;

    prep_all<<<(PREP_TOTAL + 255) / 256, 256, 0, stream>>>(x, hx, Wl, Wr, WT2, deg, cursor);
    count_deg<<<(N_EDGES + 255) / 256, 256, 0, stream>>>(dstIdx, deg);
    block_sums<<<SCAN_BLOCKS, 256, 0, stream>>>(deg, bsum);
    scan_bsums<<<1, 256, 0, stream>>>(bsum, offsets);
    write_offsets<<<SCAN_BLOCKS, 256, 0, stream>>>(deg, bsum, offsets, deg_inv);
    fill_csr<<<(N_EDGES + 255) / 256, 256, 0, stream>>>(srcIdx, dstIdx, offsets, cursor, csr);

    const unsigned short* hin = hx;
    unsigned short* hbuf[2] = { hb0, hb1 };
    for (int l = 0; l < N_LAYERS; ++l) {
        aggregate<<<AGG_BLOCKS, 256, 0, stream>>>(hin, offsets, csr, deg_inv, agg);
        if (l < N_LAYERS - 1) {
            unsigned short* hout = hbuf[l & 1];
            gemm_half<<<2 * ((N_CHUNKS + 7) / 8), 512, 0, stream>>>(
                agg, hin, WT2 + (size_t)l * 128 * 256, bl + (size_t)l * DD, hout);
            hin = hout;
        } else {
            gemm_full<<<(N_CHUNKS + 7) / 8, 512, 0, stream>>>(
                agg, hin, WT2 + (size_t)l * 128 * 256, bl + (size_t)l * DD,
                fcW, fcb, out);
        }
    }
}

// Round 19
// 343.896 us; speedup vs baseline: 1.0758x; 1.0586x over previous
//
#include <hip/hip_runtime.h>
#include <hip/hip_bf16.h>

#define N_NODES 50000
#define N_EDGES 600000
#define DD 128
#define N_LAYERS 6
#define SCAN_BLOCKS 196   // ceil(50000/256)
#define N_CHUNKS 3125     // 50000 / 16 exactly
#define AGG_BLOCKS 6256

#define XB16_T 1600000
#define ZERO_T 50000
#define PREPW_T 196608
#define PREP_TOTAL (XB16_T + ZERO_T + PREPW_T)

typedef __attribute__((ext_vector_type(8))) short bf16x8;
typedef __attribute__((ext_vector_type(4))) float floatx4;

__device__ __forceinline__ unsigned short f2b(float f) {
    unsigned u = __float_as_uint(f);
    unsigned r = (u + 0x7FFFu + ((u >> 16) & 1u)) >> 16;
    return (unsigned short)r;
}

// ---------------- merged prep ----------------

__global__ void prep_all(const float* __restrict__ x, unsigned short* __restrict__ hx,
                         const float* __restrict__ Wl, const float* __restrict__ Wr,
                         unsigned short* __restrict__ WT2,
                         int* __restrict__ deg, int* __restrict__ cursor) {
    int gid = blockIdx.x * blockDim.x + threadIdx.x;
    if (gid < XB16_T) {
        int b = gid * 4;
        float4 v = *(const float4*)(x + b);
        ushort4 o;
        o.x = f2b(v.x); o.y = f2b(v.y); o.z = f2b(v.z); o.w = f2b(v.w);
        *(ushort4*)(hx + b) = o;
    } else if (gid < XB16_T + ZERO_T) {
        int i = gid - XB16_T;
        deg[i] = 0; cursor[i] = 0;
    } else if (gid < PREP_TOTAL) {
        int idx = gid - (XB16_T + ZERO_T);
        int l   = idx >> 15;
        int rem = idx & 32767;
        int n   = rem >> 8;
        int k2  = rem & 255;
        const float* W = (k2 < 128 ? Wl : Wr) + (size_t)l * DD * DD + (size_t)(k2 & 127) * DD + n;
        WT2[idx] = f2b(*W);
    }
}

// ---------------- CSR build ----------------

__global__ void count_deg(const int* __restrict__ dst, int* __restrict__ deg) {
    int e = blockIdx.x * blockDim.x + threadIdx.x;
    if (e < N_EDGES) atomicAdd(&deg[dst[e]], 1);
}

__global__ void block_sums(const int* __restrict__ deg, int* __restrict__ bsum) {
    __shared__ int s[256];
    int tid = threadIdx.x;
    int i = blockIdx.x * 256 + tid;
    int v = (i < N_NODES) ? deg[i] : 0;
    s[tid] = v;
    __syncthreads();
    #pragma unroll
    for (int off = 128; off > 0; off >>= 1) {
        if (tid < off) s[tid] += s[tid + off];
        __syncthreads();
    }
    if (tid == 0) bsum[blockIdx.x] = s[0];
}

// merged: every block redundantly scans the 196 block sums in LDS, then does
// its per-node scan — removes the scan_bsums dispatch + boundary.
__global__ void write_offsets(const int* __restrict__ deg, const int* __restrict__ bsum,
                              int* __restrict__ offsets, float* __restrict__ deg_inv) {
    __shared__ int sb[256];
    __shared__ int s[256];
    int tid = threadIdx.x;

    int bv = (tid < SCAN_BLOCKS) ? bsum[tid] : 0;
    sb[tid] = bv;
    __syncthreads();
    for (int off = 1; off < 256; off <<= 1) {
        int t = (tid >= off) ? sb[tid - off] : 0;
        __syncthreads();
        sb[tid] += t;
        __syncthreads();
    }
    int base = (blockIdx.x == 0) ? 0 : sb[blockIdx.x - 1];

    int i = blockIdx.x * 256 + tid;
    int v = (i < N_NODES) ? deg[i] : 0;
    s[tid] = v;
    __syncthreads();
    for (int off = 1; off < 256; off <<= 1) {
        int t = (tid >= off) ? s[tid - off] : 0;
        __syncthreads();
        s[tid] += t;
        __syncthreads();
    }
    if (i < N_NODES) {
        offsets[i] = base + s[tid] - v;
        deg_inv[i] = 1.0f / (float)(v > 1 ? v : 1);
    }
    if (blockIdx.x == 0 && tid == 0) offsets[N_NODES] = N_EDGES;
}

__global__ void fill_csr(const int* __restrict__ src, const int* __restrict__ dst,
                         const int* __restrict__ offsets, int* __restrict__ cursor,
                         int* __restrict__ csr_src) {
    int e = blockIdx.x * blockDim.x + threadIdx.x;
    if (e < N_EDGES) {
        int d = dst[e];
        int p = atomicAdd(&cursor[d], 1);
        csr_src[offsets[d] + p] = src[e];
    }
}

// ---------------- mean aggregation: R12-exact (best measured) ----------------

__global__ void aggregate(const unsigned short* __restrict__ hin, const int* __restrict__ offsets,
                          const int* __restrict__ csr_src, const float* __restrict__ deg_inv,
                          unsigned short* __restrict__ agg) {
    int w    = threadIdx.x >> 6;
    int lane = threadIdx.x & 63;
    int nodeSel = lane >> 5;
    int l32  = lane & 31;
    int grp  = l32 >> 3;
    int p    = l32 & 7;

    int b = blockIdx.x;
    int x = b & 7, s = b >> 3;
    int hc = 16 * (s >> 1) + 2 * x + (s & 1);
    int node = hc * 8 + 2 * w + nodeSel;
    if (node >= N_NODES) return;
    int s0 = offsets[node], e0 = offsets[node + 1];
    float di = deg_inv[node];

    float a[16];
    #pragma unroll
    for (int i = 0; i < 16; ++i) a[i] = 0.f;

    const unsigned short* base = hin;
    int j = s0 + grp;
    for (; j + 4 < e0; j += 8) {
        int src1 = csr_src[j];
        int src2 = csr_src[j + 4];
        const uint4* r1 = (const uint4*)(base + (size_t)src1 * DD + p * 16);
        const uint4* r2 = (const uint4*)(base + (size_t)src2 * DD + p * 16);
        uint4 v1a = r1[0], v1b = r1[1];
        uint4 v2a = r2[0], v2b = r2[1];
        a[0] += __uint_as_float(v1a.x << 16); a[1] += __uint_as_float(v1a.x & 0xFFFF0000u);
        a[2] += __uint_as_float(v1a.y << 16); a[3] += __uint_as_float(v1a.y & 0xFFFF0000u);
        a[4] += __uint_as_float(v1a.z << 16); a[5] += __uint_as_float(v1a.z & 0xFFFF0000u);
        a[6] += __uint_as_float(v1a.w << 16); a[7] += __uint_as_float(v1a.w & 0xFFFF0000u);
        a[8] += __uint_as_float(v1b.x << 16); a[9] += __uint_as_float(v1b.x & 0xFFFF0000u);
        a[10]+= __uint_as_float(v1b.y << 16); a[11]+= __uint_as_float(v1b.y & 0xFFFF0000u);
        a[12]+= __uint_as_float(v1b.z << 16); a[13]+= __uint_as_float(v1b.z & 0xFFFF0000u);
        a[14]+= __uint_as_float(v1b.w << 16); a[15]+= __uint_as_float(v1b.w & 0xFFFF0000u);
        a[0] += __uint_as_float(v2a.x << 16); a[1] += __uint_as_float(v2a.x & 0xFFFF0000u);
        a[2] += __uint_as_float(v2a.y << 16); a[3] += __uint_as_float(v2a.y & 0xFFFF0000u);
        a[4] += __uint_as_float(v2a.z << 16); a[5] += __uint_as_float(v2a.z & 0xFFFF0000u);
        a[6] += __uint_as_float(v2a.w << 16); a[7] += __uint_as_float(v2a.w & 0xFFFF0000u);
        a[8] += __uint_as_float(v2b.x << 16); a[9] += __uint_as_float(v2b.x & 0xFFFF0000u);
        a[10]+= __uint_as_float(v2b.y << 16); a[11]+= __uint_as_float(v2b.y & 0xFFFF0000u);
        a[12]+= __uint_as_float(v2b.z << 16); a[13]+= __uint_as_float(v2b.z & 0xFFFF0000u);
        a[14]+= __uint_as_float(v2b.w << 16); a[15]+= __uint_as_float(v2b.w & 0xFFFF0000u);
    }
    if (j < e0) {
        int src1 = csr_src[j];
        const uint4* r1 = (const uint4*)(base + (size_t)src1 * DD + p * 16);
        uint4 v1a = r1[0], v1b = r1[1];
        a[0] += __uint_as_float(v1a.x << 16); a[1] += __uint_as_float(v1a.x & 0xFFFF0000u);
        a[2] += __uint_as_float(v1a.y << 16); a[3] += __uint_as_float(v1a.y & 0xFFFF0000u);
        a[4] += __uint_as_float(v1a.z << 16); a[5] += __uint_as_float(v1a.z & 0xFFFF0000u);
        a[6] += __uint_as_float(v1a.w << 16); a[7] += __uint_as_float(v1a.w & 0xFFFF0000u);
        a[8] += __uint_as_float(v1b.x << 16); a[9] += __uint_as_float(v1b.x & 0xFFFF0000u);
        a[10]+= __uint_as_float(v1b.y << 16); a[11]+= __uint_as_float(v1b.y & 0xFFFF0000u);
        a[12]+= __uint_as_float(v1b.z << 16); a[13]+= __uint_as_float(v1b.z & 0xFFFF0000u);
        a[14]+= __uint_as_float(v1b.w << 16); a[15]+= __uint_as_float(v1b.w & 0xFFFF0000u);
    }

    #pragma unroll
    for (int i = 0; i < 16; ++i) {
        a[i] += __shfl_xor(a[i], 8, 64);
        a[i] += __shfl_xor(a[i], 16, 64);
    }

    if (grp == 0) {
        uint4 o1, o2;
        o1.x = (unsigned)f2b(a[0] * di) | ((unsigned)f2b(a[1] * di) << 16);
        o1.y = (unsigned)f2b(a[2] * di) | ((unsigned)f2b(a[3] * di) << 16);
        o1.z = (unsigned)f2b(a[4] * di) | ((unsigned)f2b(a[5] * di) << 16);
        o1.w = (unsigned)f2b(a[6] * di) | ((unsigned)f2b(a[7] * di) << 16);
        o2.x = (unsigned)f2b(a[8] * di) | ((unsigned)f2b(a[9] * di) << 16);
        o2.y = (unsigned)f2b(a[10]* di) | ((unsigned)f2b(a[11]* di) << 16);
        o2.z = (unsigned)f2b(a[12]* di) | ((unsigned)f2b(a[13]* di) << 16);
        o2.w = (unsigned)f2b(a[14]* di) | ((unsigned)f2b(a[15]* di) << 16);
        uint4* dst = (uint4*)(agg + (size_t)node * DD + p * 16);
        dst[0] = o1;
        dst[1] = o2;
    }
}

// ---------------- GEMM (R16-exact): W in LDS, A direct from global ----------------

__launch_bounds__(512, 4)
__global__ void gemm_resW(const unsigned short* __restrict__ Agg,
                          const unsigned short* __restrict__ H,
                          const unsigned short* __restrict__ WT2,   // [128 n][256 k]
                          const float* __restrict__ bias,
                          unsigned short* __restrict__ Cout,
                          const float* __restrict__ fcW,
                          const float* __restrict__ fcb,
                          float* __restrict__ out,
                          int doFC) {
    __shared__ __align__(16) unsigned short sW[128 * 256];     // 64 KB

    int tid  = threadIdx.x;
    int wid  = tid >> 6, lane = tid & 63;
    int l15  = lane & 15, q = lane >> 4;

    for (int t = tid; t < 4096; t += 512) {
        int col = t >> 5, c = t & 31;
        uint4 v = *(const uint4*)(WT2 + (size_t)col * 256 + c * 8);
        *(uint4*)(sW + ((size_t)col * 32 + (c ^ (col & 7))) * 8) = v;
    }
    __syncthreads();

    int chunk = blockIdx.x * 8 + wid;
    if (chunk >= N_CHUNKS) return;
    int row0 = chunk * 16;

    float bcol[8];
    #pragma unroll
    for (int j = 0; j < 8; ++j) bcol[j] = bias[j * 16 + l15];

    const unsigned short* Arow = Agg + (size_t)(row0 + l15) * DD;
    const unsigned short* Hrow = H   + (size_t)(row0 + l15) * DD;
    bf16x8 aF[8];
    #pragma unroll
    for (int s = 0; s < 4; ++s)
        aF[s] = *(const bf16x8*)(Arow + (s * 4 + q) * 8);
    #pragma unroll
    for (int s = 4; s < 8; ++s)
        aF[s] = *(const bf16x8*)(Hrow + (s * 4 + q - 16) * 8);

    floatx4 acc[8];
    #pragma unroll
    for (int j = 0; j < 8; ++j) acc[j] = (floatx4){0.f, 0.f, 0.f, 0.f};

    #pragma unroll
    for (int s = 0; s < 8; ++s) {
        int cglob = s * 4 + q;
        #pragma unroll
        for (int j = 0; j < 8; ++j) {
            int col = j * 16 + l15;
            bf16x8 bF = *(const bf16x8*)(sW + ((size_t)col * 32 + (cglob ^ (col & 7))) * 8);
            acc[j] = __builtin_amdgcn_mfma_f32_16x16x32_bf16(aF[s], bF, acc[j], 0, 0, 0);
        }
    }

    if (!doFC) {
        #pragma unroll
        for (int r = 0; r < 4; ++r) {
            int row = row0 + q * 4 + r;
            #pragma unroll
            for (int j = 0; j < 8; ++j) {
                float v = acc[j][r] + bcol[j];
                Cout[(size_t)row * DD + j * 16 + l15] = f2b(fmaxf(v, 0.f));
            }
        }
    } else {
        float2 fcw[8];
        #pragma unroll
        for (int j = 0; j < 8; ++j) fcw[j] = *(const float2*)(fcW + (j * 16 + l15) * 2);
        float fb0 = fcb[0], fb1 = fcb[1];
        #pragma unroll
        for (int r = 0; r < 4; ++r) {
            float p0 = 0.f, p1 = 0.f;
            #pragma unroll
            for (int j = 0; j < 8; ++j) {
                float v = fmaxf(acc[j][r] + bcol[j], 0.f);
                p0 += v * fcw[j].x;
                p1 += v * fcw[j].y;
            }
            p0 += __shfl_xor(p0, 1, 64); p1 += __shfl_xor(p1, 1, 64);
            p0 += __shfl_xor(p0, 2, 64); p1 += __shfl_xor(p1, 2, 64);
            p0 += __shfl_xor(p0, 4, 64); p1 += __shfl_xor(p1, 4, 64);
            p0 += __shfl_xor(p0, 8, 64); p1 += __shfl_xor(p1, 8, 64);
            if (l15 == 0) {
                int row = row0 + q * 4 + r;
                out[row * 2]     = p0 + fb0;
                out[row * 2 + 1] = p1 + fb1;
            }
        }
    }
}

// ---------------- launch ----------------

extern "C" void kernel_launch(void* const* d_in, const int* in_sizes, int n_in,
                              void* d_out, int out_size, void* d_ws, size_t ws_size,
                              hipStream_t stream) {
    const float* x    = (const float*)d_in[0];
    const int*   ei   = (const int*)d_in[1];
    const float* Wl   = (const float*)d_in[2];
    const float* Wr   = (const float*)d_in[3];
    const float* bl   = (const float*)d_in[4];
    const float* fcW  = (const float*)d_in[5];
    const float* fcb  = (const float*)d_in[6];
    float* out = (float*)d_out;

    const int* srcIdx = ei;
    const int* dstIdx = ei + N_EDGES;

    char* ws = (char*)d_ws;
    size_t off = 0;
    auto bump = [&](size_t bytes) { char* p = ws + off; off = (off + bytes + 255) & ~(size_t)255; return p; };
    int*   deg     = (int*)  bump(N_NODES * 4);
    int*   cursor  = (int*)  bump(N_NODES * 4);
    int*   offsets = (int*)  bump((N_NODES + 1) * 4);
    int*   bsum    = (int*)  bump(SCAN_BLOCKS * 4);
    float* deg_inv = (float*)bump(N_NODES * 4);
    int*   csr     = (int*)  bump(N_EDGES * 4);
    unsigned short* hx   = (unsigned short*)bump((size_t)N_NODES * DD * 2);
    unsigned short* hb0  = (unsigned short*)bump((size_t)N_NODES * DD * 2);
    unsigned short* hb1  = (unsigned short*)bump((size_t)N_NODES * DD * 2);
    unsigned short* agg  = (unsigned short*)bump((size_t)N_NODES * DD * 2);
    unsigned short* WT2  = (unsigned short*)bump((size_t)N_LAYERS * 128 * 256 * 2);
    (void)ws_size;

    prep_all<<<(PREP_TOTAL + 255) / 256, 256, 0, stream>>>(x, hx, Wl, Wr, WT2, deg, cursor);
    count_deg<<<(N_EDGES + 255) / 256, 256, 0, stream>>>(dstIdx, deg);
    block_sums<<<SCAN_BLOCKS, 256, 0, stream>>>(deg, bsum);
    write_offsets<<<SCAN_BLOCKS, 256, 0, stream>>>(deg, bsum, offsets, deg_inv);
    fill_csr<<<(N_EDGES + 255) / 256, 256, 0, stream>>>(srcIdx, dstIdx, offsets, cursor, csr);

    const unsigned short* hin = hx;
    unsigned short* hbuf[2] = { hb0, hb1 };
    for (int l = 0; l < N_LAYERS; ++l) {
        int last = (l == N_LAYERS - 1);
        aggregate<<<AGG_BLOCKS, 256, 0, stream>>>(hin, offsets, csr, deg_inv, agg);
        unsigned short* hout = hbuf[l & 1];
        gemm_resW<<<(N_CHUNKS + 7) / 8, 512, 0, stream>>>(
            agg, hin, WT2 + (size_t)l * 128 * 256, bl + (size_t)l * DD, hout,
            fcW, fcb, out, last);
        hin = hout;
    }
}